// Round 10
// baseline (65.280 us; speedup 1.0000x reference)
//
#include <hip/hip_runtime.h>
#include <hip/hip_bf16.h>
#include <stdint.h>

#define S_SCALE 30.0f
#define S_LOG2E 43.2808512266689f   /* 30 * log2(e) */
#define N_ROWS 8192
#define D_DIM 256
#define C_CLS 10000
#define NCB 8

typedef __attribute__((ext_vector_type(8))) short short8;
typedef __attribute__((ext_vector_type(4))) float f32x4;
typedef __attribute__((ext_vector_type(4))) unsigned short us4;

static __device__ __forceinline__ unsigned short f2bf(float f) {
  union { float f; unsigned u; } a; a.f = f;
  unsigned r = a.u + 0x7fffu + ((a.u >> 16) & 1u);
  return (unsigned short)(r >> 16);
}

static __device__ __forceinline__ void gl16(const void* g, void* l) {
  __builtin_amdgcn_global_load_lds(
      (const __attribute__((address_space(1))) void*)g,
      (__attribute__((address_space(3))) void*)l, 16, 0, 0);
}

// 16-lane (DPP-row) sum, VALU pipe only; all lanes receive the group sum.
static __device__ __forceinline__ float row_sum16(float v) {
  union { float f; int i; } u, w;
  u.f = v;
  w.i = __builtin_amdgcn_update_dpp(0, u.i, 0xB1, 0xF, 0xF, true);  u.f += w.f; // lane^1
  w.i = __builtin_amdgcn_update_dpp(0, u.i, 0x4E, 0xF, 0xF, true);  u.f += w.f; // lane^2
  w.i = __builtin_amdgcn_update_dpp(0, u.i, 0x141, 0xF, 0xF, true); u.f += w.f; // half-mirror
  w.i = __builtin_amdgcn_update_dpp(0, u.i, 0x140, 0xF, 0xF, true); u.f += w.f; // row-mirror
  return u.f;
}

// ---- fused prep: blocks <1280 convert W to frag layout; rest normalize x ----
// WbF layout: [c16 0..639][kc 0..7][lane]16B; lane=lk*16+lr holds
// W[col=c16*16+lr][k=kc*32+lk*8 ..+8]; cols >= C_CLS zero-padded.
__global__ __launch_bounds__(256) void k_prep(const float* __restrict__ x,
                                              const float* __restrict__ W,
                                              const int* __restrict__ target,
                                              unsigned short* __restrict__ xnb,
                                              unsigned short* __restrict__ WbF,
                                              float* __restrict__ tgt) {
  if (blockIdx.x < 1280) {
    int gidx = blockIdx.x * 256 + threadIdx.x;   // 0..327679 = 640*8*64
    int lane = gidx & 63;
    int kc = (gidx >> 6) & 7;
    int c16 = gidx >> 9;
    int col = c16 * 16 + (lane & 15);
    int k0 = kc * 32 + (lane >> 4) * 8;
    us4 o0 = {0, 0, 0, 0}, o1 = {0, 0, 0, 0};
    if (col < C_CLS) {
      const float4 a = *(const float4*)(W + (size_t)col * D_DIM + k0);
      const float4 b = *(const float4*)(W + (size_t)col * D_DIM + k0 + 4);
      o0.x = f2bf(a.x); o0.y = f2bf(a.y); o0.z = f2bf(a.z); o0.w = f2bf(a.w);
      o1.x = f2bf(b.x); o1.y = f2bf(b.y); o1.z = f2bf(b.z); o1.w = f2bf(b.w);
    }
    *(us4*)(WbF + (size_t)gidx * 8) = o0;
    *(us4*)(WbF + (size_t)gidx * 8 + 4) = o1;
  } else {
    int row = (blockIdx.x - 1280) * 4 + (threadIdx.x >> 6);
    int l = threadIdx.x & 63;
    const float4 v = *(const float4*)(x + (size_t)row * D_DIM + l * 4);
    float ss = v.x * v.x + v.y * v.y + v.z * v.z + v.w * v.w;
#pragma unroll
    for (int m = 1; m < 64; m <<= 1) ss += __shfl_xor(ss, m, 64);
    float rn = 1.0f / sqrtf(ss);
    us4 o;
    o.x = f2bf(v.x * rn); o.y = f2bf(v.y * rn);
    o.z = f2bf(v.z * rn); o.w = f2bf(v.w * rn);
    *(us4*)(xnb + (size_t)row * D_DIM + l * 4) = o;
    int tc = target[row];
    const float4 b = *(const float4*)(W + (size_t)tc * D_DIM + l * 4);
    float s = v.x * b.x + v.y * b.y + v.z * b.z + v.w * b.w;
#pragma unroll
    for (int m = 1; m < 64; m <<= 1) s += __shfl_xor(s, m, 64);
    if (l == 0) tgt[row] = s * rn;
  }
}

// ------- barrier-free fused bf16 GEMM + exp-sum epilogue, 2 blocks/CU -------
// 512 blocks (2/CU), 8 waves each; A panel 128 rows (64 KB) staged ONCE into
// frag-layout LDS (lane-linear ds_read_b128, conflict-free). Wave tile 64x64
// (acc = 64 AGPR) keeps total regs ~120 -> __launch_bounds__(512,4) = 4 waves/SIMD.
// B streamed from frag-layout global (1 KB coalesced dwordx4, L2-hit), b0/b1
// register double-buffer; kc=7 prefetches next tile's kc=0 so the per-tile
// epilogue VALU hides the tile-top B latency (T14). Per-XCD colgroup (bc0=xcd*5,
// 640 KB B slice) keeps B L2-resident. Per-tile exp-sums DPP-reduced and
// accumulated in per-wave private LDS rows (no rsacc registers).
__global__ __launch_bounds__(512, 4) void k_gemm(const unsigned short* __restrict__ xnb,
                                                 const unsigned short* __restrict__ WbF,
                                                 float* __restrict__ partials) {
  __shared__ __align__(16) char lds[67584];   // A frags 64 KB @0; rsum 2 KB @65536
  const int b = blockIdx.x;
  const int cg = b & 7;                              // XCD colgroup 0..7
  const int br = b >> 3;                             // row panel 0..63 (128 rows)
  const int bc0 = cg * 5;                            // 5 consecutive 256-col tiles
  const int t = threadIdx.x;
  const int w = t >> 6, l = t & 63;
  const int wr = w >> 2, wc = w & 3;                 // 2M x 4N waves (64x64 tile)
  const int lr = l & 15, lk = l >> 4;
  float* rsumAll = (float*)(lds + 65536);            // [8 waves][64 rows]

  if (t < 512) rsumAll[t] = 0.f;                     // covered by staging barrier

  // ---- stage A panel once: slot(r16 0..7, kc 0..7) = 1 KB lane-linear ----
  {
    const char* AgL = (const char*)xnb + (size_t)br * 128 * 512 + (size_t)lr * 512 + lk * 16;
#pragma unroll
    for (int i = 0; i < 8; ++i) {
      int slot = i * 8 + (t >> 6);            // 64 slots
      int r16 = slot >> 3, kc = slot & 7;
      gl16(AgL + (size_t)r16 * 8192 + kc * 64, lds + slot * 1024);
    }
    asm volatile("s_waitcnt vmcnt(0)" ::: "memory");
    __builtin_amdgcn_sched_barrier(0);
    __builtin_amdgcn_s_barrier();
  }

  f32x4 acc[4][4];
#pragma unroll
  for (int m = 0; m < 4; m++)
#pragma unroll
    for (int n = 0; n < 4; n++) acc[m][n] = (f32x4){0.f, 0.f, 0.f, 0.f};

  // wave's A base in LDS (slot = (wr*4+fm)*8 + kc), per-lane
  const char* AwL = lds + (size_t)(wr * 4) * 8192 + (size_t)l * 16;
  // wave's B base in global frag layout, per-lane
  const char* Bw = (const char*)WbF + (size_t)(bc0 * 16 + wc * 4) * 8192 + (size_t)l * 16;
  float* rw = rsumAll + w * 64;                      // this wave's private rows

  short8 b0[4], b1[4];
#pragma unroll
  for (int fn = 0; fn < 4; ++fn) b0[fn] = *(const short8*)(Bw + fn * 8192);

  for (int tt = 0; tt < 5; ++tt) {
    auto step = [&](int kc, short8(&cur)[4], short8(&nxt)[4]) {
      if (kc < 7) {
#pragma unroll
        for (int fn = 0; fn < 4; ++fn)
          nxt[fn] = *(const short8*)(Bw + fn * 8192 + (kc + 1) * 1024);
      } else if (tt < 4) {
        // T14: prefetch next tile's kc=0 under this tile's epilogue VALU
#pragma unroll
        for (int fn = 0; fn < 4; ++fn)
          nxt[fn] = *(const short8*)(Bw + 131072 + fn * 8192);
      }
#pragma unroll
      for (int fm2 = 0; fm2 < 2; ++fm2) {
        short8 a0 = *(const short8*)(AwL + ((2 * fm2) * 8 + kc) * 1024);
        short8 a1 = *(const short8*)(AwL + ((2 * fm2 + 1) * 8 + kc) * 1024);
#pragma unroll
        for (int fn = 0; fn < 4; ++fn)
          acc[2 * fm2][fn] = __builtin_amdgcn_mfma_f32_16x16x32_bf16(a0, cur[fn], acc[2 * fm2][fn], 0, 0, 0);
#pragma unroll
        for (int fn = 0; fn < 4; ++fn)
          acc[2 * fm2 + 1][fn] = __builtin_amdgcn_mfma_f32_16x16x32_bf16(a1, cur[fn], acc[2 * fm2 + 1][fn], 0, 0, 0);
      }
    };
    step(0, b0, b1); step(1, b1, b0); step(2, b0, b1); step(3, b1, b0);
    step(4, b0, b1); step(5, b1, b0); step(6, b0, b1); step(7, b1, b0);
    // after step7: b0 holds next tile's kc=0 frags (loads still in flight)

    // ---- per-tile epilogue: exp2, DPP col-reduce, accumulate into LDS rows ----
    // 16x16 C/D: col = lane&15, row = (lane>>4)*4 + j.
    const int bc = bc0 + tt;
#pragma unroll
    for (int m = 0; m < 4; ++m) {
      float rs0 = 0.f, rs1 = 0.f, rs2 = 0.f, rs3 = 0.f;
#pragma unroll
      for (int n = 0; n < 4; ++n) {
        int col = bc * 256 + wc * 64 + n * 16 + lr;
        bool ok = (col < C_CLS);
        rs0 += ok ? __builtin_amdgcn_exp2f(acc[m][n][0] * S_LOG2E) : 0.f;
        rs1 += ok ? __builtin_amdgcn_exp2f(acc[m][n][1] * S_LOG2E) : 0.f;
        rs2 += ok ? __builtin_amdgcn_exp2f(acc[m][n][2] * S_LOG2E) : 0.f;
        rs3 += ok ? __builtin_amdgcn_exp2f(acc[m][n][3] * S_LOG2E) : 0.f;
        acc[m][n] = (f32x4){0.f, 0.f, 0.f, 0.f};
      }
      rs0 = row_sum16(rs0); rs1 = row_sum16(rs1);
      rs2 = row_sum16(rs2); rs3 = row_sum16(rs3);
      if (lr == 0) {
        int row = m * 16 + lk * 4;
        rw[row + 0] += rs0; rw[row + 1] += rs1;
        rw[row + 2] += rs2; rw[row + 3] += rs3;
      }
    }
    Bw += 131072;   // next bc tile (16 colblks * 8 kc * 1024 B)
  }

  // ---- final: combine 4 wc-waves per row, one coalesced store ----
  __syncthreads();
  if (t < 128) {
    int wr2 = t >> 6, r = t & 63;
    float sv = rsumAll[(wr2 * 4 + 0) * 64 + r] + rsumAll[(wr2 * 4 + 1) * 64 + r] +
               rsumAll[(wr2 * 4 + 2) * 64 + r] + rsumAll[(wr2 * 4 + 3) * 64 + r];
    partials[(size_t)cg * N_ROWS + (size_t)br * 128 + t] = sv;
  }
}

// ---------------- per-row loss + block partial sums ----------------
__global__ __launch_bounds__(256) void k_loss1(const float* __restrict__ partials,
                                               const float* __restrict__ tgt,
                                               float* __restrict__ bsum) {
  __shared__ float wsum[4];
  int i = blockIdx.x * 256 + threadIdx.x;
  const float* p = partials + i;
  float s = 0.f;
#pragma unroll
  for (int j = 0; j < NCB; ++j) s += p[(size_t)j * N_ROWS];
  float tl = tgt[i];
  float tcv = fminf(fmaxf(tl, -1.0f + 1e-7f), 1.0f - 1e-7f);
  const float cm = 0.95533648912560601964f;   // cos(0.3)
  const float sm = 0.29552020666133957510f;   // sin(0.3)
  float num = S_SCALE * (tcv * cm - sqrtf(fmaxf(1.0f - tcv * tcv, 0.f)) * sm);
  float sum_excl = s - __expf(S_SCALE * tl);
  float denom = __expf(num) + sum_excl;
  float L = num - __logf(denom);
#pragma unroll
  for (int m = 1; m < 64; m <<= 1) L += __shfl_xor(L, m, 64);
  int l = threadIdx.x & 63, w = threadIdx.x >> 6;
  if (l == 0) wsum[w] = L;
  __syncthreads();
  if (threadIdx.x == 0) bsum[blockIdx.x] = wsum[0] + wsum[1] + wsum[2] + wsum[3];
}

__global__ void k_loss2(const float* __restrict__ bsum, float* __restrict__ out) {
  float s = 0.f;
  for (int i = 0; i < 32; ++i) s += bsum[i];
  out[0] = -s / (float)N_ROWS;
}

// ---------------- launch ----------------
extern "C" void kernel_launch(void* const* d_in, const int* in_sizes, int n_in,
                              void* d_out, int out_size, void* d_ws, size_t ws_size,
                              hipStream_t stream) {
  const float* x = (const float*)d_in[0];
  const float* W = (const float*)d_in[1];
  const int* target = (const int*)d_in[2];
  float* out = (float*)d_out;
  char* ws = (char*)d_ws;

  unsigned short* xnb = (unsigned short*)(ws);              // 8192*256*2   = 4,194,304
  unsigned short* WbF = (unsigned short*)(ws + 4194304);    // 640*8*1024   = 5,242,880
  float* tgt = (float*)(ws + 9437184);                      // 8192*4
  float* partials = (float*)(ws + 9469952);                 // 8*8192*4     = 262,144
  float* bsum = (float*)(ws + 9732096);                     // 32*4

  k_prep<<<3328, 256, 0, stream>>>(x, W, target, xnb, WbF, tgt);
  k_gemm<<<512, 512, 0, stream>>>(xnb, WbF, partials);
  k_loss1<<<32, 256, 0, stream>>>(partials, tgt, bsum);
  k_loss2<<<1, 1, 0, stream>>>(bsum, out);
}

// Round 11
// 60.869 us; speedup vs baseline: 1.0725x; 1.0725x over previous
//
#include <hip/hip_runtime.h>
#include <hip/hip_bf16.h>
#include <stdint.h>

#define S_SCALE 30.0f
#define S_LOG2E 43.2808512266689f   /* 30 * log2(e) */
#define N_ROWS 8192
#define D_DIM 256
#define C_CLS 10000
#define NCB 8

typedef __attribute__((ext_vector_type(8))) short short8;
typedef __attribute__((ext_vector_type(4))) float f32x4;
typedef __attribute__((ext_vector_type(4))) unsigned short us4;

static __device__ __forceinline__ unsigned short f2bf(float f) {
  union { float f; unsigned u; } a; a.f = f;
  unsigned r = a.u + 0x7fffu + ((a.u >> 16) & 1u);
  return (unsigned short)(r >> 16);
}

static __device__ __forceinline__ void gl16(const void* g, void* l) {
  __builtin_amdgcn_global_load_lds(
      (const __attribute__((address_space(1))) void*)g,
      (__attribute__((address_space(3))) void*)l, 16, 0, 0);
}

// 16-lane (DPP-row) sum, VALU pipe only; all lanes receive the group sum.
static __device__ __forceinline__ float row_sum16(float v) {
  union { float f; int i; } u, w;
  u.f = v;
  w.i = __builtin_amdgcn_update_dpp(0, u.i, 0xB1, 0xF, 0xF, true);  u.f += w.f; // lane^1
  w.i = __builtin_amdgcn_update_dpp(0, u.i, 0x4E, 0xF, 0xF, true);  u.f += w.f; // lane^2
  w.i = __builtin_amdgcn_update_dpp(0, u.i, 0x141, 0xF, 0xF, true); u.f += w.f; // half-mirror
  w.i = __builtin_amdgcn_update_dpp(0, u.i, 0x140, 0xF, 0xF, true); u.f += w.f; // row-mirror
  return u.f;
}

// ---- fused prep: blocks <1280 convert W to frag layout; rest normalize x ----
// WbF layout: [c16 0..639][kc 0..7][lane]16B; lane=lk*16+lr holds
// W[col=c16*16+lr][k=kc*32+lk*8 ..+8]; cols >= C_CLS zero-padded.
__global__ __launch_bounds__(256) void k_prep(const float* __restrict__ x,
                                              const float* __restrict__ W,
                                              const int* __restrict__ target,
                                              unsigned short* __restrict__ xnb,
                                              unsigned short* __restrict__ WbF,
                                              float* __restrict__ tgt) {
  if (blockIdx.x < 1280) {
    int gidx = blockIdx.x * 256 + threadIdx.x;   // 0..327679 = 640*8*64
    int lane = gidx & 63;
    int kc = (gidx >> 6) & 7;
    int c16 = gidx >> 9;
    int col = c16 * 16 + (lane & 15);
    int k0 = kc * 32 + (lane >> 4) * 8;
    us4 o0 = {0, 0, 0, 0}, o1 = {0, 0, 0, 0};
    if (col < C_CLS) {
      const float4 a = *(const float4*)(W + (size_t)col * D_DIM + k0);
      const float4 b = *(const float4*)(W + (size_t)col * D_DIM + k0 + 4);
      o0.x = f2bf(a.x); o0.y = f2bf(a.y); o0.z = f2bf(a.z); o0.w = f2bf(a.w);
      o1.x = f2bf(b.x); o1.y = f2bf(b.y); o1.z = f2bf(b.z); o1.w = f2bf(b.w);
    }
    *(us4*)(WbF + (size_t)gidx * 8) = o0;
    *(us4*)(WbF + (size_t)gidx * 8 + 4) = o1;
  } else {
    int row = (blockIdx.x - 1280) * 4 + (threadIdx.x >> 6);
    int l = threadIdx.x & 63;
    const float4 v = *(const float4*)(x + (size_t)row * D_DIM + l * 4);
    float ss = v.x * v.x + v.y * v.y + v.z * v.z + v.w * v.w;
#pragma unroll
    for (int m = 1; m < 64; m <<= 1) ss += __shfl_xor(ss, m, 64);
    float rn = 1.0f / sqrtf(ss);
    us4 o;
    o.x = f2bf(v.x * rn); o.y = f2bf(v.y * rn);
    o.z = f2bf(v.z * rn); o.w = f2bf(v.w * rn);
    *(us4*)(xnb + (size_t)row * D_DIM + l * 4) = o;
    int tc = target[row];
    const float4 b = *(const float4*)(W + (size_t)tc * D_DIM + l * 4);
    float s = v.x * b.x + v.y * b.y + v.z * b.z + v.w * b.w;
#pragma unroll
    for (int m = 1; m < 64; m <<= 1) s += __shfl_xor(s, m, 64);
    if (l == 0) tgt[row] = s * rn;
  }
}

// ------- barrier-free fused bf16 GEMM + exp-sum epilogue, 4 waves/SIMD -------
// 512 blocks (2/CU), 8 waves each; A panel 128 rows (64 KB) staged ONCE into
// frag-layout LDS (lane-linear ds_read_b128, conflict-free). Wave tile 64x64.
// SINGLE B register buffer (32 VGPR) + per-fm A loads (8 VGPR) keep the wave
// at ~120 unified regs -> true 4 waves/SIMD under __launch_bounds__(512,4),
// NO spills (r10's b0/b1 double-buffer = 64 regs forced spilling at the 128 cap).
// Latency hiding is TLP: a wave stalls on its B L2-load while 3 others MFMA.
// Per-CU pipe check per kc-step: MFMA 1242 cyc > LDS 768 > L2-B 485 -> MFMA-bound.
// Per-tile exp-sums DPP-reduced and accumulated in per-wave private LDS rows.
__global__ __launch_bounds__(512, 4) void k_gemm(const unsigned short* __restrict__ xnb,
                                                 const unsigned short* __restrict__ WbF,
                                                 float* __restrict__ partials) {
  __shared__ __align__(16) char lds[67584];   // A frags 64 KB @0; rsum 2 KB @65536
  const int b = blockIdx.x;
  const int cg = b & 7;                              // XCD colgroup 0..7
  const int br = b >> 3;                             // row panel 0..63 (128 rows)
  const int bc0 = cg * 5;                            // 5 consecutive 256-col tiles
  const int t = threadIdx.x;
  const int w = t >> 6, l = t & 63;
  const int wr = w >> 2, wc = w & 3;                 // 2M x 4N waves (64x64 tile)
  const int lr = l & 15, lk = l >> 4;
  float* rsumAll = (float*)(lds + 65536);            // [8 waves][64 rows]

  if (t < 512) rsumAll[t] = 0.f;                     // covered by staging barrier

  // ---- stage A panel once: slot(r16 0..7, kc 0..7) = 1 KB lane-linear ----
  {
    const char* AgL = (const char*)xnb + (size_t)br * 128 * 512 + (size_t)lr * 512 + lk * 16;
#pragma unroll
    for (int i = 0; i < 8; ++i) {
      int slot = i * 8 + w;                   // 64 slots
      int r16 = slot >> 3, kc = slot & 7;
      gl16(AgL + (size_t)r16 * 8192 + kc * 64, lds + slot * 1024);
    }
    asm volatile("s_waitcnt vmcnt(0)" ::: "memory");
    __builtin_amdgcn_sched_barrier(0);
    __builtin_amdgcn_s_barrier();
  }

  f32x4 acc[4][4];
#pragma unroll
  for (int m = 0; m < 4; m++)
#pragma unroll
    for (int n = 0; n < 4; n++) acc[m][n] = (f32x4){0.f, 0.f, 0.f, 0.f};

  // wave's A base in LDS (slot = (wr*4+fm)*8 + kc), per-lane
  const char* AwL = lds + (size_t)(wr * 4) * 8192 + (size_t)l * 16;
  // wave's B base in global frag layout, per-lane
  const char* Bw = (const char*)WbF + (size_t)(bc0 * 16 + wc * 4) * 8192 + (size_t)l * 16;
  float* rw = rsumAll + w * 64;                      // this wave's private rows

  for (int tt = 0; tt < 5; ++tt) {
#pragma unroll
    for (int kc = 0; kc < 8; ++kc) {
      short8 bf[4];
#pragma unroll
      for (int fn = 0; fn < 4; ++fn)
        bf[fn] = *(const short8*)(Bw + fn * 8192 + kc * 1024);
#pragma unroll
      for (int fm = 0; fm < 4; ++fm) {
        short8 a = *(const short8*)(AwL + (fm * 8 + kc) * 1024);
#pragma unroll
        for (int fn = 0; fn < 4; ++fn)
          acc[fm][fn] = __builtin_amdgcn_mfma_f32_16x16x32_bf16(a, bf[fn], acc[fm][fn], 0, 0, 0);
      }
    }

    // ---- per-tile epilogue: exp2, DPP col-reduce, accumulate into LDS rows ----
    // 16x16 C/D: col = lane&15, row = (lane>>4)*4 + j.
    const int bc = bc0 + tt;
#pragma unroll
    for (int m = 0; m < 4; ++m) {
      float rs0 = 0.f, rs1 = 0.f, rs2 = 0.f, rs3 = 0.f;
#pragma unroll
      for (int n = 0; n < 4; ++n) {
        int col = bc * 256 + wc * 64 + n * 16 + lr;
        bool ok = (col < C_CLS);
        rs0 += ok ? __builtin_amdgcn_exp2f(acc[m][n][0] * S_LOG2E) : 0.f;
        rs1 += ok ? __builtin_amdgcn_exp2f(acc[m][n][1] * S_LOG2E) : 0.f;
        rs2 += ok ? __builtin_amdgcn_exp2f(acc[m][n][2] * S_LOG2E) : 0.f;
        rs3 += ok ? __builtin_amdgcn_exp2f(acc[m][n][3] * S_LOG2E) : 0.f;
        acc[m][n] = (f32x4){0.f, 0.f, 0.f, 0.f};
      }
      rs0 = row_sum16(rs0); rs1 = row_sum16(rs1);
      rs2 = row_sum16(rs2); rs3 = row_sum16(rs3);
      if (lr == 0) {
        int row = m * 16 + lk * 4;
        rw[row + 0] += rs0; rw[row + 1] += rs1;
        rw[row + 2] += rs2; rw[row + 3] += rs3;
      }
    }
    Bw += 131072;   // next bc tile (16 colblks * 8 kc * 1024 B)
  }

  // ---- final: combine 4 wc-waves per row, one coalesced store ----
  __syncthreads();
  if (t < 128) {
    int wr2 = t >> 6, r = t & 63;
    float sv = rsumAll[(wr2 * 4 + 0) * 64 + r] + rsumAll[(wr2 * 4 + 1) * 64 + r] +
               rsumAll[(wr2 * 4 + 2) * 64 + r] + rsumAll[(wr2 * 4 + 3) * 64 + r];
    partials[(size_t)cg * N_ROWS + (size_t)br * 128 + t] = sv;
  }
}

// ---------------- per-row loss + block partial sums ----------------
__global__ __launch_bounds__(256) void k_loss1(const float* __restrict__ partials,
                                               const float* __restrict__ tgt,
                                               float* __restrict__ bsum) {
  __shared__ float wsum[4];
  int i = blockIdx.x * 256 + threadIdx.x;
  const float* p = partials + i;
  float s = 0.f;
#pragma unroll
  for (int j = 0; j < NCB; ++j) s += p[(size_t)j * N_ROWS];
  float tl = tgt[i];
  float tcv = fminf(fmaxf(tl, -1.0f + 1e-7f), 1.0f - 1e-7f);
  const float cm = 0.95533648912560601964f;   // cos(0.3)
  const float sm = 0.29552020666133957510f;   // sin(0.3)
  float num = S_SCALE * (tcv * cm - sqrtf(fmaxf(1.0f - tcv * tcv, 0.f)) * sm);
  float sum_excl = s - __expf(S_SCALE * tl);
  float denom = __expf(num) + sum_excl;
  float L = num - __logf(denom);
#pragma unroll
  for (int m = 1; m < 64; m <<= 1) L += __shfl_xor(L, m, 64);
  int l = threadIdx.x & 63, w = threadIdx.x >> 6;
  if (l == 0) wsum[w] = L;
  __syncthreads();
  if (threadIdx.x == 0) bsum[blockIdx.x] = wsum[0] + wsum[1] + wsum[2] + wsum[3];
}

__global__ void k_loss2(const float* __restrict__ bsum, float* __restrict__ out) {
  float s = 0.f;
  for (int i = 0; i < 32; ++i) s += bsum[i];
  out[0] = -s / (float)N_ROWS;
}

// ---------------- launch ----------------
extern "C" void kernel_launch(void* const* d_in, const int* in_sizes, int n_in,
                              void* d_out, int out_size, void* d_ws, size_t ws_size,
                              hipStream_t stream) {
  const float* x = (const float*)d_in[0];
  const float* W = (const float*)d_in[1];
  const int* target = (const int*)d_in[2];
  float* out = (float*)d_out;
  char* ws = (char*)d_ws;

  unsigned short* xnb = (unsigned short*)(ws);              // 8192*256*2   = 4,194,304
  unsigned short* WbF = (unsigned short*)(ws + 4194304);    // 640*8*1024   = 5,242,880
  float* tgt = (float*)(ws + 9437184);                      // 8192*4
  float* partials = (float*)(ws + 9469952);                 // 8*8192*4     = 262,144
  float* bsum = (float*)(ws + 9732096);                     // 32*4

  k_prep<<<3328, 256, 0, stream>>>(x, W, target, xnb, WbF, tgt);
  k_gemm<<<512, 512, 0, stream>>>(xnb, WbF, partials);
  k_loss1<<<32, 256, 0, stream>>>(partials, tgt, bsum);
  k_loss2<<<1, 1, 0, stream>>>(bsum, out);
}

// Round 12
// 53.309 us; speedup vs baseline: 1.2246x; 1.1418x over previous
//
#include <hip/hip_runtime.h>
#include <hip/hip_bf16.h>
#include <stdint.h>

#define S_SCALE 30.0f
#define S_L2E_SC 0.33813165020835f  /* 30*log2(e)/128 : inputs scaled 8*16 */
#define N_ROWS 8192
#define D_DIM 256
#define C_CLS 10000
#define NCB 8

typedef __attribute__((ext_vector_type(4))) float f32x4;

static __device__ __forceinline__ void gl16(const void* g, void* l) {
  __builtin_amdgcn_global_load_lds(
      (const __attribute__((address_space(1))) void*)g,
      (__attribute__((address_space(3))) void*)l, 16, 0, 0);
}

static __device__ __forceinline__ long u2l(uint2 v) {
  union { uint2 u; long l; } x; x.u = v; return x.l;
}

// 16-lane (DPP-row) sum, VALU pipe only; all lanes receive the group sum.
static __device__ __forceinline__ float row_sum16(float v) {
  union { float f; int i; } u, w;
  u.f = v;
  w.i = __builtin_amdgcn_update_dpp(0, u.i, 0xB1, 0xF, 0xF, true);  u.f += w.f; // lane^1
  w.i = __builtin_amdgcn_update_dpp(0, u.i, 0x4E, 0xF, 0xF, true);  u.f += w.f; // lane^2
  w.i = __builtin_amdgcn_update_dpp(0, u.i, 0x141, 0xF, 0xF, true); u.f += w.f; // half-mirror
  w.i = __builtin_amdgcn_update_dpp(0, u.i, 0x140, 0xF, 0xF, true); u.f += w.f; // row-mirror
  return u.f;
}

// ---- fused prep (fp8 e4m3, pre-scaled): blocks <1280 convert W (x16) to frag
// layout; rest L2-normalize x (x8) into A-frag layout + exact fp32 target logit.
// WbF8: [c16 0..639][kc 0..7][lane]8B; lane=lk*16+lr holds W[col=c16*16+lr]
// [k=kc*32+lk*8 ..+8]; cols >= C_CLS zero. xnb8: [panel 0..63] 32KB linear frag
// blocks: byte (r16*8+kc)*512 + lane*8 within panel (row=panel*128+r16*16+lr).
__global__ __launch_bounds__(256) void k_prep(const float* __restrict__ x,
                                              const float* __restrict__ W,
                                              const int* __restrict__ target,
                                              unsigned char* __restrict__ xnb8,
                                              unsigned char* __restrict__ WbF8,
                                              float* __restrict__ tgt) {
  if (blockIdx.x < 1280) {
    int gidx = blockIdx.x * 256 + threadIdx.x;   // 0..327679 = 640*8*64
    int lane = gidx & 63;
    int kc = (gidx >> 6) & 7;
    int c16 = gidx >> 9;
    int col = c16 * 16 + (lane & 15);
    int k0 = kc * 32 + (lane >> 4) * 8;
    int r0 = 0, r1 = 0;
    if (col < C_CLS) {
      const float4 a = *(const float4*)(W + (size_t)col * D_DIM + k0);
      const float4 b = *(const float4*)(W + (size_t)col * D_DIM + k0 + 4);
      r0 = __builtin_amdgcn_cvt_pk_fp8_f32(a.x * 16.f, a.y * 16.f, 0, false);
      r0 = __builtin_amdgcn_cvt_pk_fp8_f32(a.z * 16.f, a.w * 16.f, r0, true);
      r1 = __builtin_amdgcn_cvt_pk_fp8_f32(b.x * 16.f, b.y * 16.f, 0, false);
      r1 = __builtin_amdgcn_cvt_pk_fp8_f32(b.z * 16.f, b.w * 16.f, r1, true);
    }
    *(int2*)(WbF8 + (size_t)gidx * 8) = (int2){r0, r1};
  } else {
    int row = (blockIdx.x - 1280) * 4 + (threadIdx.x >> 6);
    int l = threadIdx.x & 63;
    const float4 v = *(const float4*)(x + (size_t)row * D_DIM + l * 4);
    float ss = v.x * v.x + v.y * v.y + v.z * v.z + v.w * v.w;
#pragma unroll
    for (int m = 1; m < 64; m <<= 1) ss += __shfl_xor(ss, m, 64);
    float rn = 1.0f / sqrtf(ss);
    float s8 = rn * 8.f;
    int r0 = __builtin_amdgcn_cvt_pk_fp8_f32(v.x * s8, v.y * s8, 0, false);
    r0 = __builtin_amdgcn_cvt_pk_fp8_f32(v.z * s8, v.w * s8, r0, true);
    int j = l >> 1, e = l & 1;
    int panel = row >> 7, r16 = (row >> 4) & 7, lr = row & 15;
    size_t dst = (size_t)panel * 32768 + (size_t)(r16 * 8 + (j >> 2)) * 512 +
                 (size_t)((j & 3) * 16 + lr) * 8 + e * 4;
    *(int*)(xnb8 + dst) = r0;
    // exact fp32 target logit
    int tc = target[row];
    const float4 b = *(const float4*)(W + (size_t)tc * D_DIM + l * 4);
    float s = v.x * b.x + v.y * b.y + v.z * b.z + v.w * b.w;
#pragma unroll
    for (int m = 1; m < 64; m <<= 1) s += __shfl_xor(s, m, 64);
    if (l == 0) tgt[row] = s * rn;
  }
}

// ------- barrier-free fused fp8 GEMM + exp-sum epilogue, 4 waves/SIMD -------
// 512 blocks (2/CU), 8 waves (2Mx4N), wave tile 64x64. A panel 128 rows x 256 k
// fp8 = 32 KB LDS, staged once (linear gl16 copy; frag-order ds_read_b64,
// conflict-free). B streamed from frag-layout global (512 B coalesced dwordx2
// per frag, L2-hit) with REGISTER DOUBLE-BUFFER — fp8 frags are 2 VGPRs, so
// acc(64)+Bdbuf(16)+A(4)+addr fits ~96 regs -> true 4 waves/SIMD WITH prefetch
// (bf16 version needed 148 and spilled). L2 B-traffic also halves vs bf16.
// Inputs pre-scaled (x8 * W16 = 128); epilogue exp2(acc * S*log2e/128).
__global__ __launch_bounds__(512, 4) void k_gemm(const unsigned char* __restrict__ xnb8,
                                                 const unsigned char* __restrict__ WbF8,
                                                 float* __restrict__ partials) {
  __shared__ __align__(16) char lds[34816];   // A frags 32 KB @0; rsum 2 KB @32768
  const int b = blockIdx.x;
  const int cg = b & 7;                              // XCD colgroup 0..7
  const int br = b >> 3;                             // row panel 0..63 (128 rows)
  const int bc0 = cg * 5;                            // 5 consecutive 256-col tiles
  const int t = threadIdx.x;
  const int w = t >> 6, l = t & 63;
  const int wr = w >> 2, wc = w & 3;                 // 2M x 4N waves (64x64 tile)
  const int lr = l & 15, lk = l >> 4;
  float* rsumAll = (float*)(lds + 32768);            // [8 waves][64 rows]

  if (t < 512) rsumAll[t] = 0.f;                     // covered by staging barrier

  // ---- stage A panel once: pure linear 32 KB copy into frag-order LDS ----
  {
    const char* Ag = (const char*)xnb8 + (size_t)br * 32768;
#pragma unroll
    for (int i = 0; i < 4; ++i)
      gl16(Ag + i * 8192 + w * 1024 + l * 16, lds + i * 8192 + w * 1024);
    asm volatile("s_waitcnt vmcnt(0)" ::: "memory");
    __builtin_amdgcn_sched_barrier(0);
    __builtin_amdgcn_s_barrier();
  }

  f32x4 acc[4][4];
#pragma unroll
  for (int m = 0; m < 4; m++)
#pragma unroll
    for (int n = 0; n < 4; n++) acc[m][n] = (f32x4){0.f, 0.f, 0.f, 0.f};

  // wave's A base in LDS (slot = (wr*4+fm)*8 + kc, 512 B each), per-lane
  const char* AwL = lds + (size_t)(wr * 4 * 8) * 512 + (size_t)l * 8;
  // wave's B base in global frag layout (c16 = bc*16 + wc*4 + fn), per-lane
  const unsigned char* Bw = WbF8 + (size_t)(bc0 * 16 + wc * 4) * 4096 + (size_t)l * 8;
  float* rw = rsumAll + w * 64;                      // this wave's private rows

  uint2 b0[4], b1[4];
#pragma unroll
  for (int fn = 0; fn < 4; ++fn) b0[fn] = *(const uint2*)(Bw + fn * 4096);

  for (int tt = 0; tt < 5; ++tt) {
    auto step = [&](int kc, uint2(&cur)[4], uint2(&nxt)[4]) {
      if (kc < 7) {
#pragma unroll
        for (int fn = 0; fn < 4; ++fn)
          nxt[fn] = *(const uint2*)(Bw + fn * 4096 + (kc + 1) * 512);
      } else if (tt < 4) {
        // prefetch next tile's kc=0 under this tile's epilogue VALU
#pragma unroll
        for (int fn = 0; fn < 4; ++fn)
          nxt[fn] = *(const uint2*)(Bw + 65536 + fn * 4096);
      }
#pragma unroll
      for (int fm = 0; fm < 4; ++fm) {
        long a = u2l(*(const uint2*)(AwL + (fm * 8 + kc) * 512));
#pragma unroll
        for (int fn = 0; fn < 4; ++fn)
          acc[fm][fn] = __builtin_amdgcn_mfma_f32_16x16x32_fp8_fp8(
              a, u2l(cur[fn]), acc[fm][fn], 0, 0, 0);
      }
    };
    step(0, b0, b1); step(1, b1, b0); step(2, b0, b1); step(3, b1, b0);
    step(4, b0, b1); step(5, b1, b0); step(6, b0, b1); step(7, b1, b0);
    // after step7: b0 holds next tile's kc=0 frags (loads in flight)

    // ---- per-tile epilogue: exp2, DPP col-reduce, accumulate into LDS rows ----
    // 16x16 C/D: col = lane&15, row = (lane>>4)*4 + j.
    const int bc = bc0 + tt;
#pragma unroll
    for (int m = 0; m < 4; ++m) {
      float rs0 = 0.f, rs1 = 0.f, rs2 = 0.f, rs3 = 0.f;
#pragma unroll
      for (int n = 0; n < 4; ++n) {
        int col = bc * 256 + wc * 64 + n * 16 + lr;
        bool ok = (col < C_CLS);
        rs0 += ok ? __builtin_amdgcn_exp2f(acc[m][n][0] * S_L2E_SC) : 0.f;
        rs1 += ok ? __builtin_amdgcn_exp2f(acc[m][n][1] * S_L2E_SC) : 0.f;
        rs2 += ok ? __builtin_amdgcn_exp2f(acc[m][n][2] * S_L2E_SC) : 0.f;
        rs3 += ok ? __builtin_amdgcn_exp2f(acc[m][n][3] * S_L2E_SC) : 0.f;
        acc[m][n] = (f32x4){0.f, 0.f, 0.f, 0.f};
      }
      rs0 = row_sum16(rs0); rs1 = row_sum16(rs1);
      rs2 = row_sum16(rs2); rs3 = row_sum16(rs3);
      if (lr == 0) {
        int row = m * 16 + lk * 4;
        rw[row + 0] += rs0; rw[row + 1] += rs1;
        rw[row + 2] += rs2; rw[row + 3] += rs3;
      }
    }
    Bw += 65536;   // next bc tile (16 colblks * 8 kc * 512 B)
  }

  // ---- final: combine 4 wc-waves per row, one coalesced store ----
  __syncthreads();
  if (t < 128) {
    int wr2 = t >> 6, r = t & 63;
    float sv = rsumAll[(wr2 * 4 + 0) * 64 + r] + rsumAll[(wr2 * 4 + 1) * 64 + r] +
               rsumAll[(wr2 * 4 + 2) * 64 + r] + rsumAll[(wr2 * 4 + 3) * 64 + r];
    partials[(size_t)cg * N_ROWS + (size_t)br * 128 + t] = sv;
  }
}

// ---------------- per-row loss + block partial sums ----------------
__global__ __launch_bounds__(256) void k_loss1(const float* __restrict__ partials,
                                               const float* __restrict__ tgt,
                                               float* __restrict__ bsum) {
  __shared__ float wsum[4];
  int i = blockIdx.x * 256 + threadIdx.x;
  const float* p = partials + i;
  float s = 0.f;
#pragma unroll
  for (int j = 0; j < NCB; ++j) s += p[(size_t)j * N_ROWS];
  float tl = tgt[i];
  float tcv = fminf(fmaxf(tl, -1.0f + 1e-7f), 1.0f - 1e-7f);
  const float cm = 0.95533648912560601964f;   // cos(0.3)
  const float sm = 0.29552020666133957510f;   // sin(0.3)
  float num = S_SCALE * (tcv * cm - sqrtf(fmaxf(1.0f - tcv * tcv, 0.f)) * sm);
  float sum_excl = s - __expf(S_SCALE * tl);
  float denom = __expf(num) + sum_excl;
  float L = num - __logf(denom);
#pragma unroll
  for (int m = 1; m < 64; m <<= 1) L += __shfl_xor(L, m, 64);
  int l = threadIdx.x & 63, w = threadIdx.x >> 6;
  if (l == 0) wsum[w] = L;
  __syncthreads();
  if (threadIdx.x == 0) bsum[blockIdx.x] = wsum[0] + wsum[1] + wsum[2] + wsum[3];
}

__global__ void k_loss2(const float* __restrict__ bsum, float* __restrict__ out) {
  float s = 0.f;
  for (int i = 0; i < 32; ++i) s += bsum[i];
  out[0] = -s / (float)N_ROWS;
}

// ---------------- launch ----------------
extern "C" void kernel_launch(void* const* d_in, const int* in_sizes, int n_in,
                              void* d_out, int out_size, void* d_ws, size_t ws_size,
                              hipStream_t stream) {
  const float* x = (const float*)d_in[0];
  const float* W = (const float*)d_in[1];
  const int* target = (const int*)d_in[2];
  float* out = (float*)d_out;
  char* ws = (char*)d_ws;

  unsigned char* xnb8 = (unsigned char*)(ws);               // 8192*256     = 2,097,152
  unsigned char* WbF8 = (unsigned char*)(ws + 2097152);     // 640*8*512    = 2,621,440
  float* tgt = (float*)(ws + 4718592);                      // 8192*4
  float* partials = (float*)(ws + 4751360);                 // 8*8192*4     = 262,144
  float* bsum = (float*)(ws + 5013504);                     // 32*4

  k_prep<<<3328, 256, 0, stream>>>(x, W, target, xnb8, WbF8, tgt);
  k_gemm<<<512, 512, 0, stream>>>(xnb8, WbF8, partials);
  k_loss1<<<32, 256, 0, stream>>>(partials, tgt, bsum);
  k_loss2<<<1, 1, 0, stream>>>(bsum, out);
}